// Round 3
// baseline (141.407 us; speedup 1.0000x reference)
//
#include <hip/hip_runtime.h>
#include <cstdint>

#define MARGIN_F 0.2f

typedef __attribute__((ext_vector_type(8))) short sv8;   // 8 x bf16 (4 VGPRs)
typedef __attribute__((ext_vector_type(4))) float fv4;   // MFMA accumulator

// ---- round-to-nearest-even fp32 -> bf16 (bit pattern) ----
__device__ __forceinline__ unsigned short f2bf(float x) {
    unsigned u = __float_as_uint(x);
    unsigned r = (u + 0x7fffu + ((u >> 16) & 1u)) >> 16;
    return (unsigned short)r;
}

// ---- async global->LDS, 16B per lane (dest = wave-uniform base + lane*16) ----
__device__ __forceinline__ void gload16(const void* g, void* l) {
    __builtin_amdgcn_global_load_lds(
        (const __attribute__((address_space(1))) unsigned*)g,
        (__attribute__((address_space(3))) unsigned*)l,
        16, 0, 0);
}

// ---- swizzled LDS fragment read: tile layout [64 rows][128 bytes], XOR swizzle ----
__device__ __forceinline__ sv8 ldsfrag(const char* base, int row, int kc) {
    int byte = (row << 7) + ((kc << 1) ^ ((row & 7) << 4));
    return *(const sv8*)(base + byte);
}

// =====================================================================
// prep: norms, pos_sq, d_pos (fp32 exact) + bf16 conversion of e1,e2
// =====================================================================
__global__ __launch_bounds__(128) void prep_kernel(
    const float* __restrict__ e1, const float* __restrict__ e2,
    unsigned short* __restrict__ e1b, unsigned short* __restrict__ e2b,
    float* __restrict__ n1, float* __restrict__ n2,
    float* __restrict__ psq, float* __restrict__ dpos)
{
    const int row = blockIdx.x;
    const int t = threadIdx.x;
    const float4 a = reinterpret_cast<const float4*>(e1 + (size_t)row * 512)[t];
    const float4 b = reinterpret_cast<const float4*>(e2 + (size_t)row * 512)[t];

    ushort4 pa, pb;
    pa.x = f2bf(a.x); pa.y = f2bf(a.y); pa.z = f2bf(a.z); pa.w = f2bf(a.w);
    pb.x = f2bf(b.x); pb.y = f2bf(b.y); pb.z = f2bf(b.z); pb.w = f2bf(b.w);
    reinterpret_cast<ushort4*>(e1b + (size_t)row * 512)[t] = pa;
    reinterpret_cast<ushort4*>(e2b + (size_t)row * 512)[t] = pb;

    float s1 = a.x*a.x + a.y*a.y + a.z*a.z + a.w*a.w;
    float s2 = b.x*b.x + b.y*b.y + b.z*b.z + b.w*b.w;
    float dx = a.x-b.x, dy = a.y-b.y, dz = a.z-b.z, dw = a.w-b.w;
    float sp = dx*dx + dy*dy + dz*dz + dw*dw;

    #pragma unroll
    for (int o = 32; o; o >>= 1) {
        s1 += __shfl_down(s1, o);
        s2 += __shfl_down(s2, o);
        sp += __shfl_down(sp, o);
    }
    __shared__ float r1[2], r2[2], rp[2];
    if ((t & 63) == 0) { int wv = t >> 6; r1[wv] = s1; r2[wv] = s2; rp[wv] = sp; }
    __syncthreads();
    if (t == 0) {
        float v1 = r1[0] + r1[1];
        float v2 = r2[0] + r2[1];
        float vp = rp[0] + rp[1];
        n1[row] = v1; n2[row] = v2; psq[row] = vp; dpos[row] = sqrtf(vp);
    }
}

// =====================================================================
// main: pair-block scheme over 64x64 tiles, (bi<=bj) triangle,
// 2-phase double-buffered LDS pipeline (stage next || compute cur),
// epilogue scalars staged in LDS, fused last-block finalize.
// grid: 2080 blocks x 256 threads (4 waves, 2x2; wave region 32x32)
// =====================================================================
__global__ __launch_bounds__(256, 2) void triplet_main(
    const unsigned short* __restrict__ e1b, const unsigned short* __restrict__ e2b,
    const float* __restrict__ n1, const float* __restrict__ n2,
    const float* __restrict__ psq, const float* __restrict__ dpos,
    float* __restrict__ total, unsigned* __restrict__ count,
    unsigned* __restrict__ done, float* __restrict__ out)
{
    __shared__ char lds[67584];   // 2 staging buffers (32KB each) + 2KB scalars
    char* bA = lds;               // buffer A: A1,A2,B1,B2 at +0,+8K,+16K,+24K
    char* bB = lds + 32768;       // buffer B
    float* sc = (float*)(lds + 65536);  // [0:256) i-side, [256:512) j-side
                                        // each side: n1,n2,psq,dpos x 64

    // ---- triangular pair decode: bid -> (bi, bj), bi<=bj, 64 tiles/dim ----
    const int bid = blockIdx.x;
    int r = (int)((129.0f - sqrtf(16641.0f - 8.0f * (float)bid)) * 0.5f);
    while (64 * r - (r * (r - 1)) / 2 > bid) --r;
    while (64 * (r + 1) - ((r + 1) * r) / 2 <= bid) ++r;
    const int bi = r;
    const int bj = bi + (bid - (64 * r - (r * (r - 1)) / 2));
    const bool diag = (bi == bj);
    const int i0 = bi << 6;
    const int j0 = bj << 6;

    const int tid  = threadIdx.x;
    const int w    = tid >> 6;
    const int lane = tid & 63;
    const int l15  = lane & 15;
    const int l4   = lane >> 4;
    const int wr   = w >> 1;      // 0..1
    const int wc   = w & 1;       // 0..1

    fv4 acc11[2][2], acc22[2][2], acc12[2][2], accT[2][2];
    #pragma unroll
    for (int m = 0; m < 2; ++m)
        #pragma unroll
        for (int n = 0; n < 2; ++n) {
            acc11[m][n] = (fv4)0.0f;
            acc22[m][n] = (fv4)0.0f;
            acc12[m][n] = (fv4)0.0f;
            accT[m][n]  = (fv4)0.0f;
        }

    const char* e1c = (const char*)e1b;
    const char* e2c = (const char*)e2b;

#define STAGE(BUF, K0) do {                                                 \
    _Pragma("unroll")                                                       \
    for (int t = 0; t < 2; ++t) {                                           \
        const int chunk = tid + (t << 8);                                   \
        const int row   = chunk >> 3;                                       \
        const int scb   = ((chunk & 7) << 4) ^ ((row & 7) << 4);            \
        const long offi = (long)(i0 + row) * 1024 + ((K0) << 1) + scb;      \
        const long offj = (long)(j0 + row) * 1024 + ((K0) << 1) + scb;      \
        const int lbase = ((t << 8) + (w << 6)) << 4;                       \
        gload16(e1c + offi, (BUF) + lbase);                                 \
        gload16(e2c + offi, (BUF) + 8192 + lbase);                          \
        gload16(e1c + offj, (BUF) + 16384 + lbase);                         \
        gload16(e2c + offj, (BUF) + 24576 + lbase);                         \
    }                                                                       \
} while (0)

#define COMPUTE(BUF) do {                                                   \
    _Pragma("unroll")                                                       \
    for (int kk = 0; kk < 64; kk += 32) {                                   \
        const int kc = kk + (l4 << 3);                                      \
        sv8 a1[2], a2[2], b1[2], b2[2];                                     \
        _Pragma("unroll")                                                   \
        for (int m = 0; m < 2; ++m) {                                       \
            const int R = (wr << 5) + (m << 4) + l15;                       \
            a1[m] = ldsfrag((BUF), R, kc);                                  \
            a2[m] = ldsfrag((BUF) + 8192, R, kc);                           \
        }                                                                   \
        _Pragma("unroll")                                                   \
        for (int n = 0; n < 2; ++n) {                                       \
            const int R = (wc << 5) + (n << 4) + l15;                       \
            b1[n] = ldsfrag((BUF) + 16384, R, kc);                          \
            b2[n] = ldsfrag((BUF) + 24576, R, kc);                          \
        }                                                                   \
        _Pragma("unroll")                                                   \
        for (int m = 0; m < 2; ++m)                                         \
            _Pragma("unroll")                                               \
            for (int n = 0; n < 2; ++n) {                                   \
                acc11[m][n] = __builtin_amdgcn_mfma_f32_16x16x32_bf16(a1[m], b1[n], acc11[m][n], 0, 0, 0); \
                acc22[m][n] = __builtin_amdgcn_mfma_f32_16x16x32_bf16(a2[m], b2[n], acc22[m][n], 0, 0, 0); \
                acc12[m][n] = __builtin_amdgcn_mfma_f32_16x16x32_bf16(a1[m], b2[n], acc12[m][n], 0, 0, 0); \
            }                                                               \
        if (!diag) {                                                        \
            _Pragma("unroll")                                               \
            for (int n = 0; n < 2; ++n)                                     \
                _Pragma("unroll")                                           \
                for (int m = 0; m < 2; ++m)                                 \
                    accT[n][m] = __builtin_amdgcn_mfma_f32_16x16x32_bf16(b1[n], a2[m], accT[n][m], 0, 0, 0); \
        }                                                                   \
    }                                                                       \
} while (0)

    // ---- prologue: stage step 0 + epilogue scalars ----
    STAGE(bA, 0);
    if (tid < 128) {
        const int side = tid >> 6;              // 0: i-side, 1: j-side
        const int t = tid & 63;
        const int g = (side ? j0 : i0) + t;
        float* s = sc + (side << 8);
        s[t] = n1[g]; s[64 + t] = n2[g]; s[128 + t] = psq[g]; s[192 + t] = dpos[g];
    }
    __syncthreads();

    // ---- 2-phase pipeline: stage(next) || compute(cur), 1 barrier/step ----
    #pragma unroll
    for (int t2 = 0; t2 < 8; t2 += 2) {
        if (t2 + 1 < 8) STAGE(bB, (t2 + 1) << 6);
        COMPUTE(bA);
        __syncthreads();
        if (t2 + 2 < 8) STAGE(bA, (t2 + 2) << 6);
        COMPUTE(bB);
        __syncthreads();
    }

    // ---- fused epilogue: C/D layout col=lane&15, row=(lane>>4)*4+r ----
    float    ltot = 0.0f;
    unsigned lcnt = 0;
    const bool bt = !diag;
    const float* scI = sc;
    const float* scJ = sc + 256;

    float n1c[2], n2c[2], pcv[2], dpc[2];
    #pragma unroll
    for (int n = 0; n < 2; ++n) {
        const int cl = (wc << 5) + (n << 4) + l15;
        n1c[n] = scJ[cl]; n2c[n] = scJ[64 + cl]; pcv[n] = scJ[128 + cl]; dpc[n] = scJ[192 + cl];
    }
    float n2ic[2], pic[2], dpic[2];
    #pragma unroll
    for (int m = 0; m < 2; ++m) {
        const int il = (wr << 5) + (m << 4) + l15;
        n2ic[m] = scI[64 + il]; pic[m] = scI[128 + il]; dpic[m] = scI[192 + il];
    }

    #pragma unroll
    for (int m = 0; m < 2; ++m) {
        #pragma unroll
        for (int rr = 0; rr < 4; ++rr) {
            const int rl  = (wr << 5) + (m << 4) + (l4 << 2) + rr;
            const int row = i0 + rl;
            const float n1r = scI[rl], n2r = scI[64 + rl];
            const float pr  = scI[128 + rl], dpr = scI[192 + rl];
            #pragma unroll
            for (int n = 0; n < 2; ++n) {
                const int cc = j0 + (wc << 5) + (n << 4) + l15;
                const bool off = bt || (row != cc);

                // G11: row-term + (off-diag) symmetric col-term, shared sqrt
                float D11 = fmaxf(fmaf(-2.0f, acc11[m][n][rr], n1r + n1c[n]), 0.0f);
                float s11 = sqrtf(D11);
                if (off && pr     < D11) { lcnt++; ltot += fmaxf(MARGIN_F + dpr    - s11, 0.0f); }
                if (bt  && pcv[n] < D11) { lcnt++; ltot += fmaxf(MARGIN_F + dpc[n] - s11, 0.0f); }

                // G22: same pattern
                float D22 = fmaxf(fmaf(-2.0f, acc22[m][n][rr], n2r + n2c[n]), 0.0f);
                float s22 = sqrtf(D22);
                if (off && pr     < D22) { lcnt++; ltot += fmaxf(MARGIN_F + dpr    - s22, 0.0f); }
                if (bt  && pcv[n] < D22) { lcnt++; ltot += fmaxf(MARGIN_F + dpc[n] - s22, 0.0f); }

                // G12: D12 row-term (p[row]) + D21 col-term (p[col]), shared sqrt
                float D12 = fmaxf(fmaf(-2.0f, acc12[m][n][rr], n1r + n2c[n]), 0.0f);
                float s12 = sqrtf(D12);
                if (off && pr     < D12) { lcnt++; ltot += fmaxf(MARGIN_F + dpr    - s12, 0.0f); }
                if (off && pcv[n] < D12) { lcnt++; ltot += fmaxf(MARGIN_F + dpc[n] - s12, 0.0f); }
            }
        }
    }

    // accT = e1[bj-rows] . e2[bi-cols]^T  (off-diag only; row!=col guaranteed)
    if (bt) {
        #pragma unroll
        for (int n = 0; n < 2; ++n) {
            #pragma unroll
            for (int rr = 0; rr < 4; ++rr) {
                const int jl = (wc << 5) + (n << 4) + (l4 << 2) + rr;
                const float n1jr = scJ[jl], pjr = scJ[128 + jl], dpjr = scJ[192 + jl];
                #pragma unroll
                for (int m = 0; m < 2; ++m) {
                    float D = fmaxf(fmaf(-2.0f, accT[n][m][rr], n1jr + n2ic[m]), 0.0f);
                    float s = sqrtf(D);
                    if (pjr    < D) { lcnt++; ltot += fmaxf(MARGIN_F + dpjr    - s, 0.0f); }
                    if (pic[m] < D) { lcnt++; ltot += fmaxf(MARGIN_F + dpic[m] - s, 0.0f); }
                }
            }
        }
    }

    // ---- block reduction: wave shuffle -> LDS -> one atomic pair ----
    #pragma unroll
    for (int o = 32; o; o >>= 1) {
        ltot += __shfl_down(ltot, o);
        lcnt += __shfl_down(lcnt, o);
    }
    float*    lt = (float*)lds;            // staging area: safe after final barrier
    unsigned* lc = (unsigned*)(lds + 64);
    if (lane == 0) { lt[w] = ltot; lc[w] = lcnt; }
    __syncthreads();
    if (tid == 0) {
        float T = 0.0f; unsigned C = 0;
        #pragma unroll
        for (int x = 0; x < 4; ++x) { T += lt[x]; C += lc[x]; }
        atomicAdd(total, T);
        atomicAdd(count, C);
        __threadfence();
        unsigned prev = atomicAdd(done, 1u);
        if (prev == gridDim.x - 1) {
            // atomic RMW reads -> device-coherent across XCDs
            float    TT = atomicAdd(total, 0.0f);
            unsigned CC = atomicAdd(count, 0u);
            out[0] = TT / fmaxf((float)CC, 1.0f);
        }
    }
#undef STAGE
#undef COMPUTE
}

// =====================================================================
// Workspace layout (~8.6 MB):
//   [0,12)       : total (f32), count (u32), done (u32)   -- memset each call
//   [1024, ...)  : n1[4096], n2[4096], psq[4096], dpos[4096]  (f32)
//   [131072, ..) : e1b 4096x512 bf16 (4MB), then e2b (4MB)
// =====================================================================
extern "C" void kernel_launch(void* const* d_in, const int* in_sizes, int n_in,
                              void* d_out, int out_size, void* d_ws, size_t ws_size,
                              hipStream_t stream) {
    const float* e1 = (const float*)d_in[0];
    const float* e2 = (const float*)d_in[1];
    char* ws = (char*)d_ws;

    float*    total = (float*)ws;
    unsigned* count = (unsigned*)(ws + 4);
    unsigned* done  = (unsigned*)(ws + 8);
    float* n1   = (float*)(ws + 1024);
    float* n2   = n1 + 4096;
    float* psq  = n2 + 4096;
    float* dpos = psq + 4096;
    unsigned short* e1b = (unsigned short*)(ws + (1 << 17));
    unsigned short* e2b = e1b + (size_t)4096 * 512;

    hipMemsetAsync(ws, 0, 64, stream);
    prep_kernel<<<4096, 128, 0, stream>>>(e1, e2, e1b, e2b, n1, n2, psq, dpos);
    triplet_main<<<2080, 256, 0, stream>>>(e1b, e2b, n1, n2, psq, dpos,
                                           total, count, done, (float*)d_out);
}

// Round 4
// 98.090 us; speedup vs baseline: 1.4416x; 1.4416x over previous
//
#include <hip/hip_runtime.h>
#include <cstdint>

#define MARGIN_F 0.2f

typedef __attribute__((ext_vector_type(8))) short sv8;   // 8 x bf16 (4 VGPRs)
typedef __attribute__((ext_vector_type(4))) float fv4;   // MFMA accumulator

// ---- round-to-nearest-even fp32 -> bf16 (bit pattern) ----
__device__ __forceinline__ unsigned short f2bf(float x) {
    unsigned u = __float_as_uint(x);
    unsigned r = (u + 0x7fffu + ((u >> 16) & 1u)) >> 16;
    return (unsigned short)r;
}

// ---- async global->LDS, 16B per lane (dest = wave-uniform base + lane*16) ----
__device__ __forceinline__ void gload16(const void* g, void* l) {
    __builtin_amdgcn_global_load_lds(
        (const __attribute__((address_space(1))) unsigned*)g,
        (__attribute__((address_space(3))) unsigned*)l,
        16, 0, 0);
}

// =====================================================================
// prep: norms, d_pos (fp32 exact) + bf16 conversion of e1,e2
// =====================================================================
__global__ __launch_bounds__(128) void prep_kernel(
    const float* __restrict__ e1, const float* __restrict__ e2,
    unsigned short* __restrict__ e1b, unsigned short* __restrict__ e2b,
    float* __restrict__ n1, float* __restrict__ n2, float* __restrict__ dpos)
{
    const int row = blockIdx.x;
    const int t = threadIdx.x;
    const float4 a = reinterpret_cast<const float4*>(e1 + (size_t)row * 512)[t];
    const float4 b = reinterpret_cast<const float4*>(e2 + (size_t)row * 512)[t];

    ushort4 pa, pb;
    pa.x = f2bf(a.x); pa.y = f2bf(a.y); pa.z = f2bf(a.z); pa.w = f2bf(a.w);
    pb.x = f2bf(b.x); pb.y = f2bf(b.y); pb.z = f2bf(b.z); pb.w = f2bf(b.w);
    reinterpret_cast<ushort4*>(e1b + (size_t)row * 512)[t] = pa;
    reinterpret_cast<ushort4*>(e2b + (size_t)row * 512)[t] = pb;

    float s1 = a.x*a.x + a.y*a.y + a.z*a.z + a.w*a.w;
    float s2 = b.x*b.x + b.y*b.y + b.z*b.z + b.w*b.w;
    float dx = a.x-b.x, dy = a.y-b.y, dz = a.z-b.z, dw = a.w-b.w;
    float sp = dx*dx + dy*dy + dz*dz + dw*dw;

    #pragma unroll
    for (int o = 32; o; o >>= 1) {
        s1 += __shfl_down(s1, o);
        s2 += __shfl_down(s2, o);
        sp += __shfl_down(sp, o);
    }
    __shared__ float r1[2], r2[2], rp[2];
    if ((t & 63) == 0) { int wv = t >> 6; r1[wv] = s1; r2[wv] = s2; rp[wv] = sp; }
    __syncthreads();
    if (t == 0) {
        n1[row] = r1[0] + r1[1];
        n2[row] = r2[0] + r2[1];
        dpos[row] = sqrtf(rp[0] + rp[1]);
    }
}

// =====================================================================
// main: pair-block scheme over 64x64 tiles, (bi<=bj) triangle.
// Round-2-proven skeleton: single 32KB buffer, stage->sync->compute->sync.
// New: 4 blocks/CU, loop-invariant addressing, sqrt-domain epilogue.
// grid: 2080 blocks x 256 threads (4 waves, 2x2; wave region 32x32)
// =====================================================================
__global__ __launch_bounds__(256, 4) void triplet_main(
    const unsigned short* __restrict__ e1b, const unsigned short* __restrict__ e2b,
    const float* __restrict__ n1, const float* __restrict__ n2,
    const float* __restrict__ dpos,
    float* __restrict__ total, unsigned* __restrict__ count)
{
    __shared__ char lds[34304];          // 32KB staging + 1.5KB scalars
    char* buf = lds;                     // A1,A2,B1,B2 at +0,+8K,+16K,+24K
    float* sc = (float*)(lds + 32768);   // [0:192) i-side, [192:384) j-side
                                         // each side: n1 x64, n2 x64, dpos x64

    // ---- triangular pair decode: bid -> (bi, bj), bi<=bj, 64 tiles/dim ----
    const int bid = blockIdx.x;
    int r = (int)((129.0f - sqrtf(16641.0f - 8.0f * (float)bid)) * 0.5f);
    while (64 * r - (r * (r - 1)) / 2 > bid) --r;
    while (64 * (r + 1) - ((r + 1) * r) / 2 <= bid) ++r;
    const int bi = r;
    const int bj = bi + (bid - (64 * r - (r * (r - 1)) / 2));
    const bool diag = (bi == bj);
    const int i0 = bi << 6;
    const int j0 = bj << 6;

    const int tid  = threadIdx.x;
    const int w    = tid >> 6;
    const int lane = tid & 63;
    const int l15  = lane & 15;
    const int l4   = lane >> 4;
    const int wr   = w >> 1;      // 0..1
    const int wc   = w & 1;       // 0..1

    fv4 acc11[2][2], acc22[2][2], acc12[2][2], accT[2][2];
    #pragma unroll
    for (int m = 0; m < 2; ++m)
        #pragma unroll
        for (int n = 0; n < 2; ++n) {
            acc11[m][n] = (fv4)0.0f;
            acc22[m][n] = (fv4)0.0f;
            acc12[m][n] = (fv4)0.0f;
            accT[m][n]  = (fv4)0.0f;
        }

    const char* e1c = (const char*)e1b;
    const char* e2c = (const char*)e2b;

    // ---- loop-invariant staging addresses (k enters as +128B/step) ----
    long rbi[2], rbj[2]; int lb[2];
    #pragma unroll
    for (int t = 0; t < 2; ++t) {
        const int chunk = tid + (t << 8);          // 0..511
        const int row   = chunk >> 3;              // 0..63
        const int scb   = ((chunk & 7) << 4) ^ ((row & 7) << 4);  // pre-swizzled src
        rbi[t] = (long)(i0 + row) * 1024 + scb;
        rbj[t] = (long)(j0 + row) * 1024 + scb;
        lb[t]  = ((t << 8) + (w << 6)) << 4;       // wave-uniform + lane*16
    }

    // ---- loop-invariant ds_read bases (kk=32 is base^64; tiles/m/n are imms) --
    const int swz   = (l15 & 7) << 4;
    const int arow  = (wr << 5) + l15;
    const int brow  = (wc << 5) + l15;
    const int ab0   = (arow << 7) + ((l4 << 4) ^ swz);
    const int ab1   = ab0 ^ 64;
    const int bb0   = (brow << 7) + ((l4 << 4) ^ swz);
    const int bb1   = bb0 ^ 64;

#define LDSF(OFF) (*(const sv8*)(buf + (OFF)))

#define COMPUTE_HALF(AB, BB) do {                                            \
    sv8 a1[2], a2[2], b1[2], b2[2];                                          \
    _Pragma("unroll")                                                        \
    for (int m = 0; m < 2; ++m) {                                            \
        a1[m] = LDSF((AB) + m * 2048);                                       \
        a2[m] = LDSF(8192 + (AB) + m * 2048);                                \
    }                                                                        \
    _Pragma("unroll")                                                        \
    for (int n = 0; n < 2; ++n) {                                            \
        b1[n] = LDSF(16384 + (BB) + n * 2048);                               \
        b2[n] = LDSF(24576 + (BB) + n * 2048);                               \
    }                                                                        \
    _Pragma("unroll")                                                        \
    for (int m = 0; m < 2; ++m)                                              \
        _Pragma("unroll")                                                    \
        for (int n = 0; n < 2; ++n) {                                        \
            acc11[m][n] = __builtin_amdgcn_mfma_f32_16x16x32_bf16(a1[m], b1[n], acc11[m][n], 0, 0, 0); \
            acc22[m][n] = __builtin_amdgcn_mfma_f32_16x16x32_bf16(a2[m], b2[n], acc22[m][n], 0, 0, 0); \
            acc12[m][n] = __builtin_amdgcn_mfma_f32_16x16x32_bf16(a1[m], b2[n], acc12[m][n], 0, 0, 0); \
        }                                                                    \
    if (!diag) {                                                             \
        _Pragma("unroll")                                                    \
        for (int n = 0; n < 2; ++n)                                          \
            _Pragma("unroll")                                                \
            for (int m = 0; m < 2; ++m)                                      \
                accT[n][m] = __builtin_amdgcn_mfma_f32_16x16x32_bf16(b1[n], a2[m], accT[n][m], 0, 0, 0); \
    }                                                                        \
} while (0)

    // ---- epilogue scalar preload (n1, n2, dpos per side) ----
    if (tid < 128) {
        const int side = tid >> 6;               // 0: i-side, 1: j-side
        const int t = tid & 63;
        const int g = (side ? j0 : i0) + t;
        float* s = sc + side * 192;
        s[t] = n1[g]; s[64 + t] = n2[g]; s[128 + t] = dpos[g];
    }

    // ---- main loop: stage -> sync -> compute -> sync (round-2 proven) ----
    for (int k0 = 0; k0 < 512; k0 += 64) {
        const long kb = (long)(k0 << 1);
        #pragma unroll
        for (int t = 0; t < 2; ++t) {
            gload16(e1c + rbi[t] + kb, buf + lb[t]);
            gload16(e2c + rbi[t] + kb, buf + 8192 + lb[t]);
            gload16(e1c + rbj[t] + kb, buf + 16384 + lb[t]);
            gload16(e2c + rbj[t] + kb, buf + 24576 + lb[t]);
        }
        __syncthreads();
        COMPUTE_HALF(ab0, bb0);
        COMPUTE_HALF(ab1, bb1);
        __syncthreads();
    }

    // ---- fused epilogue: C/D layout col=lane&15, row=(lane>>4)*4+r ----
    // sqrt-domain: (p < D) <=> (d_pos < sqrt(D)); hinge = max(margin+dp-s, 0)
    float    ltot = 0.0f;
    unsigned lcnt = 0;
    const bool bt = !diag;
    const float* scI = sc;
    const float* scJ = sc + 192;

    float n1c[2], n2c[2], dpc[2], mdpc[2];
    #pragma unroll
    for (int n = 0; n < 2; ++n) {
        const int cl = (wc << 5) + (n << 4) + l15;
        n1c[n] = scJ[cl]; n2c[n] = scJ[64 + cl];
        dpc[n] = scJ[128 + cl]; mdpc[n] = dpc[n] + MARGIN_F;
    }
    float n2ic[2], dpic[2], mdpic[2];
    #pragma unroll
    for (int m = 0; m < 2; ++m) {
        const int il = (wr << 5) + (m << 4) + l15;
        n2ic[m] = scI[64 + il]; dpic[m] = scI[128 + il]; mdpic[m] = dpic[m] + MARGIN_F;
    }

    #pragma unroll
    for (int m = 0; m < 2; ++m) {
        #pragma unroll
        for (int rr = 0; rr < 4; ++rr) {
            const int rl  = (wr << 5) + (m << 4) + (l4 << 2) + rr;
            const int row = i0 + rl;
            const float n1r = scI[rl], n2r = scI[64 + rl];
            const float dpr = scI[128 + rl], mdpr = dpr + MARGIN_F;
            #pragma unroll
            for (int n = 0; n < 2; ++n) {
                const int cc = j0 + (wc << 5) + (n << 4) + l15;
                const bool off = bt || (row != cc);

                // G11: row-term + (off-diag) symmetric col-term, shared sqrt
                float s11 = sqrtf(fmaxf(fmaf(-2.0f, acc11[m][n][rr], n1r + n1c[n]), 0.0f));
                bool c;
                c = off && (dpr    < s11); lcnt += c; ltot += c ? fmaxf(mdpr    - s11, 0.0f) : 0.0f;
                c = bt  && (dpc[n] < s11); lcnt += c; ltot += c ? fmaxf(mdpc[n] - s11, 0.0f) : 0.0f;

                // G22: same pattern
                float s22 = sqrtf(fmaxf(fmaf(-2.0f, acc22[m][n][rr], n2r + n2c[n]), 0.0f));
                c = off && (dpr    < s22); lcnt += c; ltot += c ? fmaxf(mdpr    - s22, 0.0f) : 0.0f;
                c = bt  && (dpc[n] < s22); lcnt += c; ltot += c ? fmaxf(mdpc[n] - s22, 0.0f) : 0.0f;

                // G12: D12 row-term (dp[row]) + D21 col-term (dp[col]), shared sqrt
                float s12 = sqrtf(fmaxf(fmaf(-2.0f, acc12[m][n][rr], n1r + n2c[n]), 0.0f));
                c = off && (dpr    < s12); lcnt += c; ltot += c ? fmaxf(mdpr    - s12, 0.0f) : 0.0f;
                c = off && (dpc[n] < s12); lcnt += c; ltot += c ? fmaxf(mdpc[n] - s12, 0.0f) : 0.0f;
            }
        }
    }

    // accT = e1[bj-rows] . e2[bi-cols]^T  (off-diag only; row!=col guaranteed)
    if (bt) {
        #pragma unroll
        for (int n = 0; n < 2; ++n) {
            #pragma unroll
            for (int rr = 0; rr < 4; ++rr) {
                const int jl = (wc << 5) + (n << 4) + (l4 << 2) + rr;
                const float n1jr = scJ[jl], dpjr = scJ[128 + jl], mdpjr = dpjr + MARGIN_F;
                #pragma unroll
                for (int m = 0; m < 2; ++m) {
                    float s = sqrtf(fmaxf(fmaf(-2.0f, accT[n][m][rr], n1jr + n2ic[m]), 0.0f));
                    bool c;
                    c = dpjr    < s; lcnt += c; ltot += c ? fmaxf(mdpjr    - s, 0.0f) : 0.0f;
                    c = dpic[m] < s; lcnt += c; ltot += c ? fmaxf(mdpic[m] - s, 0.0f) : 0.0f;
                }
            }
        }
    }

    // ---- block reduction: wave shuffle -> LDS -> one atomic pair ----
    #pragma unroll
    for (int o = 32; o; o >>= 1) {
        ltot += __shfl_down(ltot, o);
        lcnt += __shfl_down(lcnt, o);
    }
    float*    lt = (float*)lds;            // staging area: safe after final barrier
    unsigned* lc = (unsigned*)(lds + 64);
    if (lane == 0) { lt[w] = ltot; lc[w] = lcnt; }
    __syncthreads();
    if (tid == 0) {
        float T = 0.0f; unsigned C = 0;
        #pragma unroll
        for (int x = 0; x < 4; ++x) { T += lt[x]; C += lc[x]; }
        atomicAdd(total, T);
        atomicAdd(count, C);
    }
#undef COMPUTE_HALF
#undef LDSF
}

__global__ void finalize_kernel(const float* __restrict__ total,
                                const unsigned* __restrict__ count,
                                float* __restrict__ out)
{
    out[0] = total[0] / fmaxf((float)count[0], 1.0f);
}

// =====================================================================
// Workspace layout (~8.6 MB):
//   [0,8)        : total (f32), count (u32)
//   [1024, ...)  : n1[4096], n2[4096], dpos[4096]  (f32)
//   [131072, ..) : e1b 4096x512 bf16 (4MB), then e2b (4MB)
// =====================================================================
extern "C" void kernel_launch(void* const* d_in, const int* in_sizes, int n_in,
                              void* d_out, int out_size, void* d_ws, size_t ws_size,
                              hipStream_t stream) {
    const float* e1 = (const float*)d_in[0];
    const float* e2 = (const float*)d_in[1];
    char* ws = (char*)d_ws;

    float*    total = (float*)ws;
    unsigned* count = (unsigned*)(ws + 4);
    float* n1   = (float*)(ws + 1024);
    float* n2   = n1 + 4096;
    float* dpos = n2 + 4096;
    unsigned short* e1b = (unsigned short*)(ws + (1 << 17));
    unsigned short* e2b = e1b + (size_t)4096 * 512;

    hipMemsetAsync(ws, 0, 64, stream);
    prep_kernel<<<4096, 128, 0, stream>>>(e1, e2, e1b, e2b, n1, n2, dpos);
    triplet_main<<<2080, 256, 0, stream>>>(e1b, e2b, n1, n2, dpos, total, count);
    finalize_kernel<<<1, 1, 0, stream>>>(total, count, (float*)d_out);
}

// Round 5
// 97.100 us; speedup vs baseline: 1.4563x; 1.0102x over previous
//
#include <hip/hip_runtime.h>
#include <cstdint>

#define MARGIN_F 0.2f

typedef __attribute__((ext_vector_type(8))) short sv8;   // 8 x bf16 (4 VGPRs)
typedef __attribute__((ext_vector_type(4))) float fv4;   // MFMA accumulator

// ---- round-to-nearest-even fp32 -> bf16 (bit pattern) ----
__device__ __forceinline__ unsigned short f2bf(float x) {
    unsigned u = __float_as_uint(x);
    unsigned r = (u + 0x7fffu + ((u >> 16) & 1u)) >> 16;
    return (unsigned short)r;
}

// ---- async global->LDS, 16B per lane (dest = wave-uniform base + lane*16) ----
__device__ __forceinline__ void gload16(const void* g, void* l) {
    __builtin_amdgcn_global_load_lds(
        (const __attribute__((address_space(1))) unsigned*)g,
        (__attribute__((address_space(3))) unsigned*)l,
        16, 0, 0);
}

// =====================================================================
// prep: norms, d_pos (fp32 exact) + bf16 conversion of e1,e2
// =====================================================================
__global__ __launch_bounds__(128) void prep_kernel(
    const float* __restrict__ e1, const float* __restrict__ e2,
    unsigned short* __restrict__ e1b, unsigned short* __restrict__ e2b,
    float* __restrict__ n1, float* __restrict__ n2, float* __restrict__ dpos)
{
    const int row = blockIdx.x;
    const int t = threadIdx.x;
    const float4 a = reinterpret_cast<const float4*>(e1 + (size_t)row * 512)[t];
    const float4 b = reinterpret_cast<const float4*>(e2 + (size_t)row * 512)[t];

    ushort4 pa, pb;
    pa.x = f2bf(a.x); pa.y = f2bf(a.y); pa.z = f2bf(a.z); pa.w = f2bf(a.w);
    pb.x = f2bf(b.x); pb.y = f2bf(b.y); pb.z = f2bf(b.z); pb.w = f2bf(b.w);
    reinterpret_cast<ushort4*>(e1b + (size_t)row * 512)[t] = pa;
    reinterpret_cast<ushort4*>(e2b + (size_t)row * 512)[t] = pb;

    float s1 = a.x*a.x + a.y*a.y + a.z*a.z + a.w*a.w;
    float s2 = b.x*b.x + b.y*b.y + b.z*b.z + b.w*b.w;
    float dx = a.x-b.x, dy = a.y-b.y, dz = a.z-b.z, dw = a.w-b.w;
    float sp = dx*dx + dy*dy + dz*dz + dw*dw;

    #pragma unroll
    for (int o = 32; o; o >>= 1) {
        s1 += __shfl_down(s1, o);
        s2 += __shfl_down(s2, o);
        sp += __shfl_down(sp, o);
    }
    __shared__ float r1[2], r2[2], rp[2];
    if ((t & 63) == 0) { int wv = t >> 6; r1[wv] = s1; r2[wv] = s2; rp[wv] = sp; }
    __syncthreads();
    if (t == 0) {
        n1[row] = r1[0] + r1[1];
        n2[row] = r2[0] + r2[1];
        dpos[row] = sqrtf(rp[0] + rp[1]);
    }
}

// =====================================================================
// main: ONE launch, 2080 blocks, three gram flavors on 128x128 tiles:
//   bid <  1024 : G12 = e1 . e2^T, FULL 32x32 grid (D12 row + D21 col terms)
//   bid <  1552 : G11 = e1 . e1^T, triangle bi<=bj (row + symmetric col terms)
//   bid >= 1552 : G22 = e2 . e2^T, triangle
// Structure: 4 waves (2x2, 64x64/wave), BK=64, LDS double buffer 2x32KB,
// raw s_barrier + counted s_waitcnt vmcnt(8) (T3+T4), setprio MFMA (T5).
// =====================================================================
__global__ __launch_bounds__(256, 2) void triplet_main(
    const unsigned short* __restrict__ e1b, const unsigned short* __restrict__ e2b,
    const float* __restrict__ n1, const float* __restrict__ n2,
    const float* __restrict__ dpos,
    float* __restrict__ total, unsigned* __restrict__ count)
{
    // [0,32K) buf0 | [32K,64K) buf1 | scalars | reduce scratch
    __shared__ char lds[67648];
    float* scRN = (float*)(lds + 65536);   // rowN[128]
    float* scRD = (float*)(lds + 66048);   // rowDP[128]
    float* scCN = (float*)(lds + 66560);   // colN[128]
    float* scCD = (float*)(lds + 67072);   // colDP[128]

    // ---- block decode ----
    const int bid = blockIdx.x;
    int bi, bj, flavor;
    if (bid < 1024) { flavor = 0; bi = bid >> 5; bj = bid & 31; }
    else {
        int b = bid - 1024; flavor = 1;
        if (b >= 528) { b -= 528; flavor = 2; }
        int r = (int)((65.0f - sqrtf(4225.0f - 8.0f * (float)b)) * 0.5f);
        while (32 * r - (r * (r - 1)) / 2 > b) --r;
        while (32 * (r + 1) - ((r + 1) * r) / 2 <= b) ++r;
        bi = r; bj = r + (b - (32 * r - (r * (r - 1)) / 2));
    }
    const int i0 = bi << 7, j0 = bj << 7;
    const char* Xc = (const char*)((flavor == 2) ? e2b : e1b);   // i-side rows
    const char* Yc = (const char*)((flavor == 1) ? e1b : e2b);   // j-side rows
    const float* nR = (flavor == 2) ? n2 : n1;
    const float* nC = (flavor == 1) ? n1 : n2;
    const bool emitCol = (flavor == 0) || (i0 != j0);
    const bool needNeq = (i0 == j0);

    const int tid  = threadIdx.x;
    const int w    = tid >> 6;
    const int lane = tid & 63;
    const int l15  = lane & 15;
    const int l4   = lane >> 4;
    const int wr   = w >> 1;      // 0..1
    const int wc   = w & 1;       // 0..1

    // ---- scalar preload FIRST (its compiler-inserted vmcnt wait happens
    //      before the pipeline's counted waits) ----
    if (tid < 128)      { scRN[tid] = nR[i0 + tid];  scRD[tid] = dpos[i0 + tid]; }
    else if (tid < 256) { int t = tid - 128; scCN[t] = nC[j0 + t]; scCD[t] = dpos[j0 + t]; }

    // ---- staging: 2 tiles x 16KB per K-step; 8 gload16/thread ----
    // dest linear: chunk = tid + c*256; tile = chunk>>10 (c<4: i-side, c>=4: j-side)
    // source pre-swizzled so swizzled ds_read sees linear k (rule 21)
    int offc[8];
    #pragma unroll
    for (int c = 0; c < 8; ++c) {
        const int chunk = tid + (c << 8);
        const int w1k   = chunk & 1023;
        const int row   = w1k >> 3;              // 0..127
        const int xb    = (w1k & 7) << 4;        // 16B slot in 128B row
        offc[c] = row * 1024 + (xb ^ ((row & 7) << 4));
    }
    const char* baseI = Xc + (long)i0 * 1024;
    const char* baseJ = Yc + (long)j0 * 1024;
    const int ldst = (w << 10);                  // wave-uniform dest base part

#define STAGE(BOFF, T) do {                                                  \
    const long kb_ = (long)((T) << 7);                                       \
    _Pragma("unroll")                                                        \
    for (int c = 0; c < 4; ++c)                                              \
        gload16(baseI + offc[c] + kb_, lds + (BOFF) + (c << 12) + ldst);     \
    _Pragma("unroll")                                                        \
    for (int c = 4; c < 8; ++c)                                              \
        gload16(baseJ + offc[c] + kb_, lds + (BOFF) + (c << 12) + ldst);     \
} while (0)

    // ---- swizzled ds_read frag bases; m/n step +2048, k-half = ^64 ----
    const int swz = (l15 & 7) << 4;
    const int aB  = ((wr << 6) + l15) * 128 + ((l4 << 4) ^ swz);
    const int bB  = 16384 + ((wc << 6) + l15) * 128 + ((l4 << 4) ^ swz);

    fv4 acc[4][4];
    #pragma unroll
    for (int m = 0; m < 4; ++m)
        #pragma unroll
        for (int n = 0; n < 4; ++n) acc[m][n] = (fv4)0.0f;

#define CHALF(BOFF, H) do {                                                  \
    sv8 a_[4], b_[4];                                                        \
    _Pragma("unroll")                                                        \
    for (int m = 0; m < 4; ++m)                                              \
        a_[m] = *(const sv8*)(lds + (BOFF) + ((aB + m * 2048) ^ (H)));       \
    _Pragma("unroll")                                                        \
    for (int n = 0; n < 4; ++n)                                              \
        b_[n] = *(const sv8*)(lds + (BOFF) + ((bB + n * 2048) ^ (H)));       \
    __builtin_amdgcn_s_setprio(1);                                           \
    _Pragma("unroll")                                                        \
    for (int m = 0; m < 4; ++m)                                              \
        _Pragma("unroll")                                                    \
        for (int n = 0; n < 4; ++n)                                          \
            acc[m][n] = __builtin_amdgcn_mfma_f32_16x16x32_bf16(             \
                a_[m], b_[n], acc[m][n], 0, 0, 0);                           \
    __builtin_amdgcn_s_setprio(0);                                           \
} while (0)

    // ---- prologue: prefetch tiles 0,1; counted wait for tile 0 only ----
    STAGE(0, 0);
    STAGE(32768, 1);
    asm volatile("s_waitcnt vmcnt(8)" ::: "memory");   // tile0 landed, tile1 in flight
    asm volatile("s_barrier" ::: "memory");

    // ---- pipelined K-loop: compute t while t+1 in flight, prefetch t+2 ----
    #pragma unroll
    for (int t = 0; t < 8; ++t) {
        const int boff = (t & 1) ? 32768 : 0;
        CHALF(boff, 0);
        CHALF(boff, 64);
        if (t == 7) break;
        asm volatile("s_barrier" ::: "memory");        // all waves done reading buf[t&1]
        if (t < 6) {
            STAGE(boff, t + 2);                        // overwrite just-read buffer
            asm volatile("s_waitcnt vmcnt(8)" ::: "memory");  // tile t+1 landed
        } else {
            asm volatile("s_waitcnt vmcnt(0)" ::: "memory");  // drain tile 7
        }
        asm volatile("s_barrier" ::: "memory");        // buf[(t+1)&1] ready for all
    }

    // ---- fused epilogue (sqrt-domain, proven r4): col=lane&15, row=l4*4+rr --
    float    ltot = 0.0f;
    unsigned lcnt = 0;

    float cNv[4], cDv[4], cMv[4];
    #pragma unroll
    for (int n = 0; n < 4; ++n) {
        const int cl = (wc << 6) + (n << 4) + l15;
        cNv[n] = scCN[cl]; cDv[n] = scCD[cl]; cMv[n] = cDv[n] + MARGIN_F;
    }

    #pragma unroll
    for (int m = 0; m < 4; ++m) {
        #pragma unroll
        for (int rr = 0; rr < 4; ++rr) {
            const int rl = (wr << 6) + (m << 4) + (l4 << 2) + rr;
            const float rN = scRN[rl], rD = scRD[rl], rM = rD + MARGIN_F;
            #pragma unroll
            for (int n = 0; n < 4; ++n) {
                const int cl = (wc << 6) + (n << 4) + l15;
                const float s = sqrtf(fmaxf(fmaf(-2.0f, acc[m][n][rr], rN + cNv[n]), 0.0f));
                const bool neq = (!needNeq) || (rl != cl);
                bool c1 = neq && (rD < s);
                lcnt += c1; ltot += c1 ? fmaxf(rM - s, 0.0f) : 0.0f;
                bool c2 = emitCol && neq && (cDv[n] < s);
                lcnt += c2; ltot += c2 ? fmaxf(cMv[n] - s, 0.0f) : 0.0f;
            }
        }
    }

    // ---- block reduction: wave shuffle -> LDS scratch -> one atomic pair ----
    #pragma unroll
    for (int o = 32; o; o >>= 1) {
        ltot += __shfl_down(ltot, o);
        lcnt += __shfl_down(lcnt, o);
    }
    float*    lt = (float*)(lds + 67584);
    unsigned* lc = (unsigned*)(lds + 67600);
    if (lane == 0) { lt[w] = ltot; lc[w] = lcnt; }
    asm volatile("s_waitcnt lgkmcnt(0)" ::: "memory");
    asm volatile("s_barrier" ::: "memory");
    if (tid == 0) {
        float T = 0.0f; unsigned C = 0;
        #pragma unroll
        for (int x = 0; x < 4; ++x) { T += lt[x]; C += lc[x]; }
        atomicAdd(total, T);
        atomicAdd(count, C);
    }
#undef STAGE
#undef CHALF
}

__global__ void finalize_kernel(const float* __restrict__ total,
                                const unsigned* __restrict__ count,
                                float* __restrict__ out)
{
    out[0] = total[0] / fmaxf((float)count[0], 1.0f);
}

// =====================================================================
// Workspace layout (~8.6 MB):
//   [0,8)        : total (f32), count (u32)
//   [1024, ...)  : n1[4096], n2[4096], dpos[4096]  (f32)
//   [131072, ..) : e1b 4096x512 bf16 (4MB), then e2b (4MB)
// =====================================================================
extern "C" void kernel_launch(void* const* d_in, const int* in_sizes, int n_in,
                              void* d_out, int out_size, void* d_ws, size_t ws_size,
                              hipStream_t stream) {
    const float* e1 = (const float*)d_in[0];
    const float* e2 = (const float*)d_in[1];
    char* ws = (char*)d_ws;

    float*    total = (float*)ws;
    unsigned* count = (unsigned*)(ws + 4);
    float* n1   = (float*)(ws + 1024);
    float* n2   = n1 + 4096;
    float* dpos = n2 + 4096;
    unsigned short* e1b = (unsigned short*)(ws + (1 << 17));
    unsigned short* e2b = e1b + (size_t)4096 * 512;

    hipMemsetAsync(ws, 0, 64, stream);
    prep_kernel<<<4096, 128, 0, stream>>>(e1, e2, e1b, e2b, n1, n2, dpos);
    triplet_main<<<2080, 256, 0, stream>>>(e1b, e2b, n1, n2, dpos, total, count);
    finalize_kernel<<<1, 1, 0, stream>>>(total, count, (float*)d_out);
}